// Round 18
// baseline (96.434 us; speedup 1.0000x reference)
//
#include <hip/hip_runtime.h>
#include <math.h>

// Problem constants: V=50000, D=100, B=16, S=128, U=100, L=2
#define NB 16
#define SS 128
#define DD 100
#define KK 100
#define T_TILE 8            // output positions per block
#define P_HALO 11           // T_TILE + 3 (dependency cone)
#define NTILES 16           // SS / T_TILE
#define NT 768              // threads per block (12 waves, 3/SIMD)
#define NWAVES 12
#define CH_D4 5             // d4-rows per chunk
#define NCHUNK 5            // 25 d4-rows total (D=100)

__device__ __forceinline__ float dot4(const float4 a, const float4 b) {
  return a.x * b.x + a.y * b.y + a.z * b.z + a.w * b.w;
}

// ---------------------------------------------------------------------------
// Per-chunk accumulate for BOTH of a wave's slots (same k-half -> V fragments
// read ONCE and reused). MODE 0: complex x (stage 1). MODE 1: real x (2, 3).
// ---------------------------------------------------------------------------
template<int MODE>
__device__ __forceinline__ void accum_pair(
    const float4* __restrict__ vtb,
    const float4 (*__restrict__ bxr)[25], const float4 (*__restrict__ bxi)[25],
    int p0, int p1, bool a0, bool a1, int k, int c,
    float& r0a, float& i0a, float& r1a, float& i1a)
{
#pragma unroll
  for (int r = 0; r < CH_D4; ++r) {
    const int d4 = c * CH_D4 + r;
    const float4 vr4 = vtb[r * KK + k];          // read once,
    const float4 vi4 = vtb[500 + r * KK + k];    // used by both slots
    if (a0) {
      const float4 x4 = bxr[p0][d4];
      if (MODE == 0) {
        const float4 z4 = bxi[p0][d4];
        r0a += dot4(vr4, x4) + dot4(vi4, z4);
        i0a += dot4(vr4, z4) - dot4(vi4, x4);
      } else {
        r0a += dot4(vr4, x4);
        i0a += dot4(vi4, x4);
      }
    }
    if (a1) {
      const float4 x4 = bxr[p1][d4];
      if (MODE == 0) {
        const float4 z4 = bxi[p1][d4];
        r1a += dot4(vr4, x4) + dot4(vi4, z4);
        i1a += dot4(vr4, z4) - dot4(vi4, x4);
      } else {
        r1a += dot4(vr4, x4);
        i1a += dot4(vi4, x4);
      }
    }
  }
}

// ---------------------------------------------------------------------------
// One projection stage: row-norm pass, chunked double-buffered transpose of
// the 100x100 complex matrix into LDS, dot products for all slots.
// MODE 0: writes m[p][k] = (ar^2+ai^2)*invvn[k].  MODE 1: writes y2 = (ar,ai).
// Caller must __syncthreads() after return before consuming outputs.
// ---------------------------------------------------------------------------
template<int MODE>
__device__ __forceinline__ void run_stage(
    const float* __restrict__ gvr, const float* __restrict__ gvi,
    float4 (*__restrict__ vt)[1000],
    const float4 (*__restrict__ bxr)[25], const float4 (*__restrict__ bxi)[25],
    float* __restrict__ mflat, float2* __restrict__ y2flat,
    float* __restrict__ invvn, const int nslots,
    const int tid, const int lane, const int wid)
{
  // --- row norms of this stage's matrix (4 lanes per row) ---
  if (tid < 4 * KK) {
    const int k = tid >> 2, q = tid & 3;
    const float* r0 = gvr + k * DD + q;
    const float* i0 = gvi + k * DD + q;
    float s = 0.f;
#pragma unroll
    for (int i = 0; i < 25; ++i) { const float a = r0[4*i], c2 = i0[4*i]; s += a*a + c2*c2; }
    s += __shfl_xor(s, 1, 64);
    s += __shfl_xor(s, 2, 64);
    if (q == 0) invvn[k] = 1.0f / s;
  }

  // element e of a chunk: part=e/500, r=(e%500)/100, k=e%100
  // global source: gv_part + k*DD + 4*(c*CH_D4 + r)   (16B aligned)
  const int e0 = tid;                 // always < 1000
  const int e1 = tid + NT;            // valid for tid < 232
  const int p0 = e0 / 500, rm0 = e0 % 500, r0_ = rm0 / 100, k0_ = rm0 % 100;
  const int p1 = e1 / 500, rm1 = e1 % 500, r1_ = rm1 / 100, k1_ = rm1 % 100;
  const float* g0 = (p0 ? gvi : gvr) + k0_ * DD + 4 * r0_;
  const float* g1 = (p1 ? gvi : gvr) + k1_ * DD + 4 * r1_;

  float4 pv0, pv1;
  pv0 = *(const float4*)(g0);                      // chunk 0
  if (e1 < 1000) pv1 = *(const float4*)(g1);
  vt[0][e0] = pv0;
  if (e1 < 1000) vt[0][e1] = pv1;
  __syncthreads();

  const int s0 = wid, s1 = wid + NWAVES;
  float a0r = 0.f, a0i = 0.f, a1r = 0.f, a1i = 0.f;
  const int kk = (s0 & 1) * 50 + lane;     // s0 and s1 share parity -> same k
  const int pp0 = s0 >> 1, pp1 = s1 >> 1;
  const bool act0 = (s0 < nslots), act1 = (s1 < nslots);

  for (int c = 0; c < NCHUNK; ++c) {
    const int buf = c & 1;
    if (c + 1 < NCHUNK) {                           // issue next-chunk loads early
      pv0 = *(const float4*)(g0 + 4 * CH_D4 * (c + 1));
      if (e1 < 1000) pv1 = *(const float4*)(g1 + 4 * CH_D4 * (c + 1));
    }
    if (lane < 50)
      accum_pair<MODE>(vt[buf], bxr, bxi, pp0, pp1, act0, act1, kk, c,
                       a0r, a0i, a1r, a1i);
    if (c + 1 < NCHUNK) {                           // write-late into other buffer
      const int nb = buf ^ 1;
      vt[nb][e0] = pv0;
      if (e1 < 1000) vt[nb][e1] = pv1;
    }
    __syncthreads();
  }

  if (lane < 50) {
    if (act0) {
      if (MODE == 0) mflat[pp0 * KK + kk] = (a0r * a0r + a0i * a0i) * invvn[kk];
      else           y2flat[pp0 * KK + kk] = make_float2(a0r, a0i);
    }
    if (act1) {
      if (MODE == 0) mflat[pp1 * KK + kk] = (a1r * a1r + a1i * a1i) * invvn[kk];
      else           y2flat[pp1 * KK + kk] = make_float2(a1r, a1i);
    }
  }
}

// ---------------------------------------------------------------------------
// Fused kernel: block = (batch, tile of 8 positions). Computes the full
// 3-stage pipeline for its halo cone (11 positions); writes partial probs;
// the LAST tile-block of each batch (device-scope counter) also performs the
// final reduction + dense layer for that batch (replaces the k_out kernel).
// ---------------------------------------------------------------------------
__global__ __launch_bounds__(NT) void k_fused(
    const int* __restrict__ seq,
    const float* __restrict__ ampT, const float* __restrict__ phT,
    const float* __restrict__ pkr, const float* __restrict__ pki,
    const float* __restrict__ mkr, const float* __restrict__ mki,
    const float* __restrict__ dw, const float* __restrict__ db,
    float* __restrict__ part, unsigned* __restrict__ cnt,
    float* __restrict__ out)
{
  __shared__ float4 vt[2][1000];        // 32000 B: V chunk double-buffer
  __shared__ float4 xr4[P_HALO][25];    // stage-1 phi real
  __shared__ float4 xi4[P_HALO][25];    // stage-1 phi imag
  __shared__ float4 m4[P_HALO][25];     // m vector (m1, then m2, then scratch)
  __shared__ float2 y2[P_HALO][KK];     // projection pair outputs
  __shared__ float es[SS];
  __shared__ float wnl[SS];
  __shared__ float invvn[KK];
  __shared__ float redw[NWAVES];
  __shared__ float sc[3];               // E, Z1, Z2
  __shared__ float pr[KK];
  __shared__ int fin;

  const int tid  = threadIdx.x;
  const int lane = tid & 63;
  const int wid  = tid >> 6;
  const int bt   = blockIdx.x;
  const int b    = bt >> 4;
  const int tile = bt & 15;
  const int t0   = tile * T_TILE;
  const int sb   = b * SS;

  // --- prologue A: norms + exp for ALL 128 positions of this batch ---
  if (tid < 4 * SS) {                   // waves 0..7 exactly
    const int t = tid >> 2, q = tid & 3;
    const int row = seq[sb + t];
    const float* ap = ampT + (long)row * DD + q;
    float s = 0.f;
#pragma unroll
    for (int i = 0; i < 25; ++i) { const float a = ap[4*i]; s += a * a; }
    s += __shfl_xor(s, 1, 64);
    s += __shfl_xor(s, 2, 64);
    if (q == 0) { const float nrm = sqrtf(s); wnl[t] = nrm; es[t] = expf(nrm); }
  }
  __syncthreads();

  // --- E and closed-form softmax denominators ---
  {
    float v = (tid < SS) ? es[tid] : 0.f;
    for (int m = 32; m; m >>= 1) v += __shfl_xor(v, m, 64);
    if (lane == 0) redw[wid] = v;
  }
  // --- prologue B: phi = (amp/||amp||) * e^{i phase} for halo positions ---
  for (int idx = tid; idx < P_HALO * 25; idx += NT) {
    const int p = idx / 25, d4 = idx % 25;
    const int tp = t0 + p;
    float4 o_r = {0.f, 0.f, 0.f, 0.f}, o_i = {0.f, 0.f, 0.f, 0.f};
    if (tp < SS) {
      const int row = seq[sb + tp];
      const float4 a4 = *(const float4*)(ampT + (long)row * DD + 4 * d4);
      const float4 p4 = *(const float4*)(phT  + (long)row * DD + 4 * d4);
      const float inv = 1.0f / wnl[tp];
      float sv, cv;
      sincosf(p4.x, &sv, &cv); o_r.x = a4.x * inv * cv; o_i.x = a4.x * inv * sv;
      sincosf(p4.y, &sv, &cv); o_r.y = a4.y * inv * cv; o_i.y = a4.y * inv * sv;
      sincosf(p4.z, &sv, &cv); o_r.z = a4.z * inv * cv; o_i.z = a4.z * inv * sv;
      sincosf(p4.w, &sv, &cv); o_r.w = a4.w * inv * cv; o_i.w = a4.w * inv * sv;
    }
    xr4[p][d4] = o_r;
    xi4[p][d4] = o_i;
  }
  __syncthreads();
  if (tid == 0) {
    float E = 0.f;
    for (int w = 0; w < NWAVES; ++w) E += redw[w];
    sc[0] = E;
    sc[1] = E - es[0] + 1.0f;
    sc[2] = E - es[0] - es[1] + 2.0f;
  }
  __syncthreads();

  // --- stage 1: m1[p][k] = |<v0_k, phi_p>|^2 / ||v0_k||^2 ---
  run_stage<0>(pkr, pki, vt, xr4, xi4, (float*)m4, nullptr, invvn,
               2 * P_HALO, tid, lane, wid);
  __syncthreads();

  // --- stage 2: y2[p][k] = (sum vr*m1, sum vi*m1) for proj layer 1 ---
  run_stage<1>(pkr + DD * DD, pki + DD * DD, vt, m4, m4, nullptr,
               (float2*)y2, invvn, 2 * P_HALO, tid, lane, wid);
  __syncthreads();

  // --- m2 = 2-tap window of y2, squared, scaled by invvn (layer-1 norms) ---
  {
    const float E = sc[0], Z1 = sc[1];
    for (int idx = tid; idx < 10 * KK; idx += NT) {
      const int p = idx / KK, k = idx - p * KK;
      const int t = t0 + p;
      const float w0 = ((t     < SS) ? es[t]     : 1.f) / E;
      const float w1 = ((t + 1 < SS) ? es[t + 1] : 1.f) / Z1;
      const float2 ya = y2[p][k], yb = y2[p + 1][k];
      const float ar = w0 * ya.x + w1 * yb.x;
      const float ai = w0 * ya.y + w1 * yb.y;
      ((float*)m4)[p * KK + k] = (ar * ar + ai * ai) * invvn[k];
    }
  }
  __syncthreads();

  // --- stage 3: y2[p][k] = (sum ur*m2, sum ui*m2), p < 10 ---
  run_stage<1>(mkr, mki, vt, m4, m4, nullptr,
               (float2*)y2, invvn, 20, tid, lane, wid);
  __syncthreads();

  // --- final: 3-tap window, square, * wn[t] * invvn_U[k]; sum over own p ---
  {
    const float E = sc[0], Z1 = sc[1], Z2 = sc[2];
    for (int idx = tid; idx < T_TILE * KK; idx += NT) {
      const int p = idx / KK, k = idx - p * KK;
      const int t = t0 + p;                         // < 128 always
      const float w0 = es[t] / E;
      const float w1 = ((t + 1 < SS) ? es[t + 1] : 1.f) / Z1;
      const float w2 = ((t + 2 < SS) ? es[t + 2] : 1.f) / Z2;
      const float2 ya = y2[p][k], yb = y2[p + 1][k], yc = y2[p + 2][k];
      const float qr = w0 * ya.x + w1 * yb.x + w2 * yc.x;
      const float qi = w0 * ya.y + w1 * yb.y + w2 * yc.y;
      ((float*)m4)[p * KK + k] = wnl[t] * (qr * qr + qi * qi) * invvn[k];
    }
  }
  __syncthreads();
  if (tid < KK) {
    float s = 0.f;
#pragma unroll
    for (int p = 0; p < T_TILE; ++p) s += ((float*)m4)[p * KK + tid];
    part[bt * KK + tid] = s;
  }

  // --- fused output: last tile-block of each batch reduces + dense layer ---
  __threadfence();                       // release: part rows visible device-wide
  __syncthreads();
  if (tid == 0) {
    const unsigned old = atomicAdd(&cnt[b], 1u);   // device-scope
    fin = (old == NTILES - 1) ? 1 : 0;
  }
  __syncthreads();
  if (fin) {
    __threadfence();                     // acquire: see all 16 tiles' part rows
    if (tid < KK) {
      float s = 0.f;
#pragma unroll
      for (int q = 0; q < NTILES; ++q) s += part[(b * NTILES + q) * KK + tid];
      pr[tid] = s;
    }
    __syncthreads();
    if (tid < 2) {
      float s = db[tid];
      for (int k = 0; k < KK; ++k) s += pr[k] * dw[k * 2 + tid];
      out[b * 2 + tid] = s;
    }
  }
}

// ---------------------------------------------------------------------------
extern "C" void kernel_launch(void* const* d_in, const int* in_sizes, int n_in,
                              void* d_out, int out_size, void* d_ws, size_t ws_size,
                              hipStream_t stream) {
  const int*   seq  = (const int*)d_in[0];
  const float* ampT = (const float*)d_in[1];
  const float* phT  = (const float*)d_in[2];
  const float* pkr  = (const float*)d_in[3];
  const float* pki  = (const float*)d_in[4];
  const float* mkr  = (const float*)d_in[5];
  const float* mki  = (const float*)d_in[6];
  const float* dw   = (const float*)d_in[7];
  const float* db   = (const float*)d_in[8];
  float* out = (float*)d_out;

  float*    ws   = (float*)d_ws;
  unsigned* cnt  = (unsigned*)d_ws;           // [16] counters (one cache line ea. not needed)
  float*    part = ws + 64;                   // [256][100] floats

  hipMemsetAsync(cnt, 0, 64 * sizeof(unsigned) > 256 ? 256 : 256, stream); // zero 256B counter region
  k_fused<<<NB * NTILES, NT, 0, stream>>>(seq, ampT, phT, pkr, pki, mkr, mki,
                                          dw, db, part, cnt, out);
}

// Round 19
// 33.845 us; speedup vs baseline: 2.8493x; 2.8493x over previous
//
#include <hip/hip_runtime.h>
#include <math.h>

// Problem constants: V=50000, D=100, B=16, S=128, U=100, L=2
#define NB 16
#define SS 128
#define DD 100
#define KK 100
#define T_TILE 8            // output positions per block
#define P_HALO 11           // T_TILE + 3 (dependency cone)
#define NTILES 16           // SS / T_TILE
#define NT 768              // threads per block (12 waves, 3/SIMD)
#define NWAVES 12
#define CH_D4 5             // d4-rows per chunk
#define NCHUNK 5            // 25 d4-rows total (D=100)

__device__ __forceinline__ float dot4(const float4 a, const float4 b) {
  return a.x * b.x + a.y * b.y + a.z * b.z + a.w * b.w;
}

// ---------------------------------------------------------------------------
// Per-chunk accumulate for BOTH of a wave's slots (same k-half -> V fragments
// read ONCE and reused; explicit CSE of the champion's two accum_slot calls).
// MODE 0: complex x (stage 1).  MODE 1: real x (stages 2, 3).
// ---------------------------------------------------------------------------
template<int MODE>
__device__ __forceinline__ void accum_pair(
    const float4* __restrict__ vtb,
    const float4 (*__restrict__ bxr)[25], const float4 (*__restrict__ bxi)[25],
    int p0, int p1, bool a0, bool a1, int k, int c,
    float& r0a, float& i0a, float& r1a, float& i1a)
{
#pragma unroll
  for (int r = 0; r < CH_D4; ++r) {
    const int d4 = c * CH_D4 + r;
    const float4 vr4 = vtb[r * KK + k];          // read once,
    const float4 vi4 = vtb[500 + r * KK + k];    // used by both slots
    if (a0) {
      const float4 x4 = bxr[p0][d4];
      if (MODE == 0) {
        const float4 z4 = bxi[p0][d4];
        r0a += dot4(vr4, x4) + dot4(vi4, z4);
        i0a += dot4(vr4, z4) - dot4(vi4, x4);
      } else {
        r0a += dot4(vr4, x4);
        i0a += dot4(vi4, x4);
      }
    }
    if (a1) {
      const float4 x4 = bxr[p1][d4];
      if (MODE == 0) {
        const float4 z4 = bxi[p1][d4];
        r1a += dot4(vr4, x4) + dot4(vi4, z4);
        i1a += dot4(vr4, z4) - dot4(vi4, x4);
      } else {
        r1a += dot4(vr4, x4);
        i1a += dot4(vi4, x4);
      }
    }
  }
}

// ---------------------------------------------------------------------------
// One projection stage: row-norm pass, chunked double-buffered transpose of
// the 100x100 complex matrix into LDS, dot products for all slots.
// MODE 0: writes m[p][k] = (ar^2+ai^2)*invvn[k].  MODE 1: writes y2 = (ar,ai).
// Caller must __syncthreads() after return before consuming outputs.
// ---------------------------------------------------------------------------
template<int MODE>
__device__ __forceinline__ void run_stage(
    const float* __restrict__ gvr, const float* __restrict__ gvi,
    float4 (*__restrict__ vt)[1000],
    const float4 (*__restrict__ bxr)[25], const float4 (*__restrict__ bxi)[25],
    float* __restrict__ mflat, float2* __restrict__ y2flat,
    float* __restrict__ invvn, const int nslots,
    const int tid, const int lane, const int wid)
{
  // --- row norms of this stage's matrix (4 lanes per row) ---
  if (tid < 4 * KK) {
    const int k = tid >> 2, q = tid & 3;
    const float* r0 = gvr + k * DD + q;
    const float* i0 = gvi + k * DD + q;
    float s = 0.f;
#pragma unroll
    for (int i = 0; i < 25; ++i) { const float a = r0[4*i], c2 = i0[4*i]; s += a*a + c2*c2; }
    s += __shfl_xor(s, 1, 64);
    s += __shfl_xor(s, 2, 64);
    if (q == 0) invvn[k] = 1.0f / s;
  }

  // element e of a chunk: part=e/500, r=(e%500)/100, k=e%100
  // global source: gv_part + k*DD + 4*(c*CH_D4 + r)   (16B aligned)
  const int e0 = tid;                 // always < 1000
  const int e1 = tid + NT;            // valid for tid < 232
  const int p0 = e0 / 500, rm0 = e0 % 500, r0_ = rm0 / 100, k0_ = rm0 % 100;
  const int p1 = e1 / 500, rm1 = e1 % 500, r1_ = rm1 / 100, k1_ = rm1 % 100;
  const float* g0 = (p0 ? gvi : gvr) + k0_ * DD + 4 * r0_;
  const float* g1 = (p1 ? gvi : gvr) + k1_ * DD + 4 * r1_;

  float4 pv0, pv1;
  pv0 = *(const float4*)(g0);                      // chunk 0
  if (e1 < 1000) pv1 = *(const float4*)(g1);
  vt[0][e0] = pv0;
  if (e1 < 1000) vt[0][e1] = pv1;
  __syncthreads();

  const int s0 = wid, s1 = wid + NWAVES;
  float a0r = 0.f, a0i = 0.f, a1r = 0.f, a1i = 0.f;
  const int kk = (s0 & 1) * 50 + lane;     // s0 and s1 share parity -> same k
  const int pp0 = s0 >> 1, pp1 = s1 >> 1;
  const bool act0 = (s0 < nslots), act1 = (s1 < nslots);

  for (int c = 0; c < NCHUNK; ++c) {
    const int buf = c & 1;
    if (c + 1 < NCHUNK) {                           // issue next-chunk loads early
      pv0 = *(const float4*)(g0 + 4 * CH_D4 * (c + 1));
      if (e1 < 1000) pv1 = *(const float4*)(g1 + 4 * CH_D4 * (c + 1));
    }
    if (lane < 50)
      accum_pair<MODE>(vt[buf], bxr, bxi, pp0, pp1, act0, act1, kk, c,
                       a0r, a0i, a1r, a1i);
    if (c + 1 < NCHUNK) {                           // write-late into other buffer
      const int nb = buf ^ 1;
      vt[nb][e0] = pv0;
      if (e1 < 1000) vt[nb][e1] = pv1;
    }
    __syncthreads();
  }

  if (lane < 50) {
    if (act0) {
      if (MODE == 0) mflat[pp0 * KK + kk] = (a0r * a0r + a0i * a0i) * invvn[kk];
      else           y2flat[pp0 * KK + kk] = make_float2(a0r, a0i);
    }
    if (act1) {
      if (MODE == 0) mflat[pp1 * KK + kk] = (a1r * a1r + a1i * a1i) * invvn[kk];
      else           y2flat[pp1 * KK + kk] = make_float2(a1r, a1i);
    }
  }
}

// ---------------------------------------------------------------------------
// Fused kernel: block = (batch, tile of 8 positions). Computes the full
// 3-stage pipeline for its halo cone (11 positions) and writes partial probs.
// ---------------------------------------------------------------------------
__global__ __launch_bounds__(NT) void k_fused(
    const int* __restrict__ seq,
    const float* __restrict__ ampT, const float* __restrict__ phT,
    const float* __restrict__ pkr, const float* __restrict__ pki,
    const float* __restrict__ mkr, const float* __restrict__ mki,
    float* __restrict__ part)
{
  __shared__ float4 vt[2][1000];        // 32000 B: V chunk double-buffer
  __shared__ float4 xr4[P_HALO][25];    // stage-1 phi real
  __shared__ float4 xi4[P_HALO][25];    // stage-1 phi imag
  __shared__ float4 m4[P_HALO][25];     // m vector (m1, then m2, then scratch)
  __shared__ float2 y2[P_HALO][KK];     // projection pair outputs
  __shared__ float es[SS];
  __shared__ float wnl[SS];
  __shared__ float invvn[KK];
  __shared__ float redw[NWAVES];
  __shared__ float sc[3];               // E, Z1, Z2

  const int tid  = threadIdx.x;
  const int lane = tid & 63;
  const int wid  = tid >> 6;
  const int bt   = blockIdx.x;
  const int b    = bt >> 4;
  const int tile = bt & 15;
  const int t0   = tile * T_TILE;
  const int sb   = b * SS;

  // --- prologue A: norms + exp for ALL 128 positions of this batch ---
  if (tid < 4 * SS) {                   // waves 0..7 exactly
    const int t = tid >> 2, q = tid & 3;
    const int row = seq[sb + t];
    const float* ap = ampT + (long)row * DD + q;
    float s = 0.f;
#pragma unroll
    for (int i = 0; i < 25; ++i) { const float a = ap[4*i]; s += a * a; }
    s += __shfl_xor(s, 1, 64);
    s += __shfl_xor(s, 2, 64);
    if (q == 0) { const float nrm = sqrtf(s); wnl[t] = nrm; es[t] = expf(nrm); }
  }
  __syncthreads();

  // --- E and closed-form softmax denominators ---
  {
    float v = (tid < SS) ? es[tid] : 0.f;
    for (int m = 32; m; m >>= 1) v += __shfl_xor(v, m, 64);
    if (lane == 0) redw[wid] = v;
  }
  // --- prologue B: phi = (amp/||amp||) * e^{i phase} for halo positions ---
  for (int idx = tid; idx < P_HALO * 25; idx += NT) {
    const int p = idx / 25, d4 = idx % 25;
    const int tp = t0 + p;
    float4 o_r = {0.f, 0.f, 0.f, 0.f}, o_i = {0.f, 0.f, 0.f, 0.f};
    if (tp < SS) {
      const int row = seq[sb + tp];
      const float4 a4 = *(const float4*)(ampT + (long)row * DD + 4 * d4);
      const float4 p4 = *(const float4*)(phT  + (long)row * DD + 4 * d4);
      const float inv = 1.0f / wnl[tp];
      float sv, cv;
      sincosf(p4.x, &sv, &cv); o_r.x = a4.x * inv * cv; o_i.x = a4.x * inv * sv;
      sincosf(p4.y, &sv, &cv); o_r.y = a4.y * inv * cv; o_i.y = a4.y * inv * sv;
      sincosf(p4.z, &sv, &cv); o_r.z = a4.z * inv * cv; o_i.z = a4.z * inv * sv;
      sincosf(p4.w, &sv, &cv); o_r.w = a4.w * inv * cv; o_i.w = a4.w * inv * sv;
    }
    xr4[p][d4] = o_r;
    xi4[p][d4] = o_i;
  }
  __syncthreads();
  if (tid == 0) {
    float E = 0.f;
    for (int w = 0; w < NWAVES; ++w) E += redw[w];
    sc[0] = E;
    sc[1] = E - es[0] + 1.0f;
    sc[2] = E - es[0] - es[1] + 2.0f;
  }
  __syncthreads();

  // --- stage 1: m1[p][k] = |<v0_k, phi_p>|^2 / ||v0_k||^2 ---
  run_stage<0>(pkr, pki, vt, xr4, xi4, (float*)m4, nullptr, invvn,
               2 * P_HALO, tid, lane, wid);
  __syncthreads();

  // --- stage 2: y2[p][k] = (sum vr*m1, sum vi*m1) for proj layer 1 ---
  run_stage<1>(pkr + DD * DD, pki + DD * DD, vt, m4, m4, nullptr,
               (float2*)y2, invvn, 2 * P_HALO, tid, lane, wid);
  __syncthreads();

  // --- m2 = 2-tap window of y2, squared, scaled by invvn (layer-1 norms) ---
  {
    const float E = sc[0], Z1 = sc[1];
    for (int idx = tid; idx < 10 * KK; idx += NT) {
      const int p = idx / KK, k = idx - p * KK;
      const int t = t0 + p;
      const float w0 = ((t     < SS) ? es[t]     : 1.f) / E;
      const float w1 = ((t + 1 < SS) ? es[t + 1] : 1.f) / Z1;
      const float2 ya = y2[p][k], yb = y2[p + 1][k];
      const float ar = w0 * ya.x + w1 * yb.x;
      const float ai = w0 * ya.y + w1 * yb.y;
      ((float*)m4)[p * KK + k] = (ar * ar + ai * ai) * invvn[k];
    }
  }
  __syncthreads();

  // --- stage 3: y2[p][k] = (sum ur*m2, sum ui*m2), p < 10 ---
  run_stage<1>(mkr, mki, vt, m4, m4, nullptr,
               (float2*)y2, invvn, 20, tid, lane, wid);
  __syncthreads();

  // --- final: 3-tap window, square, * wn[t] * invvn_U[k]; sum over own p ---
  {
    const float E = sc[0], Z1 = sc[1], Z2 = sc[2];
    for (int idx = tid; idx < T_TILE * KK; idx += NT) {
      const int p = idx / KK, k = idx - p * KK;
      const int t = t0 + p;                         // < 128 always
      const float w0 = es[t] / E;
      const float w1 = ((t + 1 < SS) ? es[t + 1] : 1.f) / Z1;
      const float w2 = ((t + 2 < SS) ? es[t + 2] : 1.f) / Z2;
      const float2 ya = y2[p][k], yb = y2[p + 1][k], yc = y2[p + 2][k];
      const float qr = w0 * ya.x + w1 * yb.x + w2 * yc.x;
      const float qi = w0 * ya.y + w1 * yb.y + w2 * yc.y;
      ((float*)m4)[p * KK + k] = wnl[t] * (qr * qr + qi * qi) * invvn[k];
    }
  }
  __syncthreads();
  if (tid < KK) {
    float s = 0.f;
#pragma unroll
    for (int p = 0; p < T_TILE; ++p) s += ((float*)m4)[p * KK + tid];
    part[bt * KK + tid] = s;
  }
}

// ---------------------------------------------------------------------------
// Output: probs[b,k] = sum_tiles part; out = probs @ dense_w + dense_b
// ---------------------------------------------------------------------------
__global__ __launch_bounds__(128) void k_out(
    const float* __restrict__ part, const float* __restrict__ dw,
    const float* __restrict__ db, float* __restrict__ out)
{
  __shared__ float pr[KK];
  const int b = blockIdx.x, tid = threadIdx.x;
  if (tid < KK) {
    float s = 0.f;
#pragma unroll
    for (int q = 0; q < NTILES; ++q) s += part[(b * NTILES + q) * KK + tid];
    pr[tid] = s;
  }
  __syncthreads();
  if (tid < 2) {
    float s = db[tid];
    for (int k = 0; k < KK; ++k) s += pr[k] * dw[k * 2 + tid];
    out[b * 2 + tid] = s;
  }
}

// ---------------------------------------------------------------------------
extern "C" void kernel_launch(void* const* d_in, const int* in_sizes, int n_in,
                              void* d_out, int out_size, void* d_ws, size_t ws_size,
                              hipStream_t stream) {
  const int*   seq  = (const int*)d_in[0];
  const float* ampT = (const float*)d_in[1];
  const float* phT  = (const float*)d_in[2];
  const float* pkr  = (const float*)d_in[3];
  const float* pki  = (const float*)d_in[4];
  const float* mkr  = (const float*)d_in[5];
  const float* mki  = (const float*)d_in[6];
  const float* dw   = (const float*)d_in[7];
  const float* db   = (const float*)d_in[8];
  float* out  = (float*)d_out;
  float* part = (float*)d_ws;                 // 256*100 floats = 102.4 KB

  k_fused<<<NB * NTILES, NT, 0, stream>>>(seq, ampT, phT, pkr, pki, mkr, mki, part);
  k_out  <<<NB,          128, 0, stream>>>(part, dw, db, out);
}